// Round 2
// baseline (294.823 us; speedup 1.0000x reference)
//
#include <hip/hip_runtime.h>

// out[n,0,p,Y,Z] = sum_k y[n,k,0,Y/4,Z/4] * W[k,0,p,Y%4,Z%4]
// y: (8,128,1,16,16)  W: (128,1,1024,4,4)  out: (8,1,1024,64,64)
//
// Lane map: zz = lane&15, q = lane>>4. Thread tile: 4 yy x 4 p x 4 r.
// Wave stores are fully coalesced: for fixed (i,j), lane = q*16+zz covers
// 256 consecutive floats -> one 1 KiB contiguous store per instruction.
// W loads don't depend on zz -> 16-lane broadcast, L1-served.

#define Y_N_STRIDE   32768     // 128*16*16
#define W_K_STRIDE   16384     // 1024*4*4
#define OUT_N_STRIDE 4194304   // 1024*64*64

__global__ __launch_bounds__(256, 4)
void backproj_kernel(const float* __restrict__ y,
                     const float* __restrict__ W,
                     float* __restrict__ out) {
    const int tid  = threadIdx.x;
    const int lane = tid & 63;
    const int zz   = lane & 15;       // z-block index (16)
    const int q    = (lane >> 4) & 3; // b2 index (4)
    const int wave = tid >> 6;        // 0..3

    const int bid = blockIdx.x;
    const int pc  = bid & 63;         // p chunk (64 chunks of 16)
    const int yyg = (bid >> 6) & 3;   // yy group (4 groups of 4)
    const int n   = bid >> 8;         // batch (8)

    const int p0  = pc * 16 + wave * 4;  // this thread's 4 p values
    const int yy0 = yyg * 4;             // this thread's 4 yy values

    // y[n, k, yy0+i, zz] = yb[k*256 + i*16]
    const float* yb = y + n * Y_N_STRIDE + yy0 * 16 + zz;
    // W[k, p0+j, q, 0..3] = Wb[k*16384 + j*16 .. +3]
    const float* Wb = W + p0 * 16 + q * 4;

    float acc[4][4][4]; // [yy][p][r]
    #pragma unroll
    for (int i = 0; i < 4; ++i)
        #pragma unroll
        for (int j = 0; j < 4; ++j)
            #pragma unroll
            for (int r = 0; r < 4; ++r)
                acc[i][j][r] = 0.0f;

    // unroll 2 (not 4): keeps live range ~120 VGPR, under the 128-VGPR cap
    // implied by __launch_bounds__(256,4); unroll 4 would spill.
    #pragma unroll 2
    for (int k = 0; k < 128; ++k) {
        float yv[4];
        #pragma unroll
        for (int i = 0; i < 4; ++i)
            yv[i] = yb[k * 256 + i * 16];

        float4 wv[4];
        #pragma unroll
        for (int j = 0; j < 4; ++j)
            wv[j] = *reinterpret_cast<const float4*>(Wb + k * W_K_STRIDE + j * 16);

        #pragma unroll
        for (int i = 0; i < 4; ++i) {
            #pragma unroll
            for (int j = 0; j < 4; ++j) {
                acc[i][j][0] = fmaf(yv[i], wv[j].x, acc[i][j][0]);
                acc[i][j][1] = fmaf(yv[i], wv[j].y, acc[i][j][1]);
                acc[i][j][2] = fmaf(yv[i], wv[j].z, acc[i][j][2]);
                acc[i][j][3] = fmaf(yv[i], wv[j].w, acc[i][j][3]);
            }
        }
    }

    // out[n, p0+j, (yy0+i)*4+q, zz*4 + 0..3]
    float* ob = out + (size_t)n * OUT_N_STRIDE + zz * 4;
    #pragma unroll
    for (int i = 0; i < 4; ++i) {
        const int Y = (yy0 + i) * 4 + q;
        #pragma unroll
        for (int j = 0; j < 4; ++j) {
            float4 v = make_float4(acc[i][j][0], acc[i][j][1],
                                   acc[i][j][2], acc[i][j][3]);
            *reinterpret_cast<float4*>(ob + (p0 + j) * 4096 + Y * 64) = v;
        }
    }
}

extern "C" void kernel_launch(void* const* d_in, const int* in_sizes, int n_in,
                              void* d_out, int out_size, void* d_ws, size_t ws_size,
                              hipStream_t stream) {
    const float* y = (const float*)d_in[0];
    const float* W = (const float*)d_in[1];
    float* out = (float*)d_out;

    // grid: 8 n * 4 yy-groups * 64 p-chunks
    dim3 grid(2048);
    dim3 block(256);
    backproj_kernel<<<grid, block, 0, stream>>>(y, W, out);
}

// Round 4
// 262.005 us; speedup vs baseline: 1.1253x; 1.1253x over previous
//
#include <hip/hip_runtime.h>

// out[n,0,p,Y,Z] = sum_k y[n,k,0,Y/4,Z/4] * W[k,0,p,Y%4,Z%4]
// y: (8,128,1,16,16)  W: (128,1,1024,4,4)  out: (8,1,1024,64,64)
//
// R3/R4: latency fix. R2 showed VALUBusy=32% with ideal memory traffic ->
// exposed global-load latency (load -> waitcnt -> FMA serial chain).
// (1) y staged in LDS once per block (shared by all 4 waves; removes 4
//     global loads/iter from the chain).
// (2) W loads software-pipelined one k ahead (in flight under the FMAs).

#define Y_N_STRIDE   32768     // 128*16*16
#define W_K_STRIDE   16384     // 1024*4*4
#define OUT_N_STRIDE 4194304   // 1024*64*64

__global__ __launch_bounds__(256, 4)
void backproj_kernel(const float* __restrict__ y,
                     const float* __restrict__ W,
                     float* __restrict__ out) {
    // y_s[k][i*16+zz]  (i = yy - yy0): 128*64 floats = 32 KiB
    __shared__ float y_s[128 * 64];

    const int tid  = threadIdx.x;
    const int lane = tid & 63;
    const int zz   = lane & 15;       // z-block index (16)
    const int q    = (lane >> 4) & 3; // b2 index (4)
    const int wave = tid >> 6;        // 0..3

    const int bid = blockIdx.x;
    const int pc  = bid & 63;         // p chunk (64 chunks of 16)
    const int yyg = (bid >> 6) & 3;   // yy group (4 groups of 4)
    const int n   = bid >> 8;         // batch (8)

    const int p0  = pc * 16 + wave * 4;  // this thread's 4 p values
    const int yy0 = yyg * 4;             // this thread's 4 yy values

    // ---- stage y into LDS: 8192 floats = 2048 float4, 8 per thread ----
    // For fixed k, y[n,k,yy0..yy0+3,0..15] is 64 contiguous floats, and the
    // LDS layout is the same flat order -> float4 idx f: lds[f*4] <- yb[...]
    {
        const float* yb = y + n * Y_N_STRIDE + yy0 * 16;
        #pragma unroll
        for (int r = 0; r < 8; ++r) {
            const int f = tid + r * 256;        // float4 index in [0,2048)
            const int k = f >> 4;               // 16 float4 per k-row
            const int c = (f & 15) * 4;
            float4 v = *reinterpret_cast<const float4*>(yb + k * 256 + c);
            *reinterpret_cast<float4*>(&y_s[f * 4]) = v;
        }
    }
    __syncthreads();

    // W[k, p0+j, q, 0..3] = Wb[k*16384 + j*16 .. +3]
    const float* Wb = W + p0 * 16 + q * 4;

    float acc[4][4][4]; // [yy][p][r]
    #pragma unroll
    for (int i = 0; i < 4; ++i)
        #pragma unroll
        for (int j = 0; j < 4; ++j)
            #pragma unroll
            for (int r = 0; r < 4; ++r)
                acc[i][j][r] = 0.0f;

    // prefetch W for k=0
    float4 wv[4];
    #pragma unroll
    for (int j = 0; j < 4; ++j)
        wv[j] = *reinterpret_cast<const float4*>(Wb + j * 16);

    #pragma unroll 1
    for (int k = 0; k < 128; ++k) {
        // issue next-k W loads first; they fly under this k's FMAs
        float4 wn[4];
        if (k < 127) {
            #pragma unroll
            for (int j = 0; j < 4; ++j)
                wn[j] = *reinterpret_cast<const float4*>(
                            Wb + (k + 1) * W_K_STRIDE + j * 16);
        }

        // y from LDS: 16 consecutive dwords x 4-lane broadcast -> conflict-free
        float yv[4];
        #pragma unroll
        for (int i = 0; i < 4; ++i)
            yv[i] = y_s[k * 64 + i * 16 + zz];

        #pragma unroll
        for (int i = 0; i < 4; ++i) {
            #pragma unroll
            for (int j = 0; j < 4; ++j) {
                acc[i][j][0] = fmaf(yv[i], wv[j].x, acc[i][j][0]);
                acc[i][j][1] = fmaf(yv[i], wv[j].y, acc[i][j][1]);
                acc[i][j][2] = fmaf(yv[i], wv[j].z, acc[i][j][2]);
                acc[i][j][3] = fmaf(yv[i], wv[j].w, acc[i][j][3]);
            }
        }

        #pragma unroll
        for (int j = 0; j < 4; ++j)
            wv[j] = wn[j];
    }

    // out[n, p0+j, (yy0+i)*4+q, zz*4 + 0..3] — 1 KiB contiguous per wave instr
    float* ob = out + (size_t)n * OUT_N_STRIDE + zz * 4;
    #pragma unroll
    for (int i = 0; i < 4; ++i) {
        const int Y = (yy0 + i) * 4 + q;
        #pragma unroll
        for (int j = 0; j < 4; ++j) {
            float4 v = make_float4(acc[i][j][0], acc[i][j][1],
                                   acc[i][j][2], acc[i][j][3]);
            *reinterpret_cast<float4*>(ob + (p0 + j) * 4096 + Y * 64) = v;
        }
    }
}

extern "C" void kernel_launch(void* const* d_in, const int* in_sizes, int n_in,
                              void* d_out, int out_size, void* d_ws, size_t ws_size,
                              hipStream_t stream) {
    const float* y = (const float*)d_in[0];
    const float* W = (const float*)d_in[1];
    float* out = (float*)d_out;

    // grid: 8 n * 4 yy-groups * 64 p-chunks
    dim3 grid(2048);
    dim3 block(256);
    backproj_kernel<<<grid, block, 0, stream>>>(y, W, out);
}

// Round 8
// 247.080 us; speedup vs baseline: 1.1932x; 1.0604x over previous
//
#include <hip/hip_runtime.h>

// out[n,0,p,Y,Z] = sum_k y[n,k,0,Y/4,Z/4] * W[k,0,p,Y%4,Z%4]
// y: (8,128,1,16,16)  W: (128,1,1024,4,4)  out: (8,1,1024,64,64)
//
// R5..R8: VALU-overhead + latency fix on top of R4 (165us, VALUBusy 54%).
//  - k unrolled x2 with named A/B W buffers -> no register-copy v_movs.
//  - y_s stored transposed [k][z][i] -> one ds_read_b128 per k per thread
//    (immediate offsets for all k; 2-way bank aliasing is free).
//  - W loads keep distance-1 prefetch, flying under 64 FMAs each.

#define Y_N_STRIDE   32768     // 128*16*16
#define W_K_STRIDE   16384     // 1024*4*4
#define OUT_N_STRIDE 4194304   // 1024*64*64

__global__ __launch_bounds__(256, 4)
void backproj_kernel(const float* __restrict__ y,
                     const float* __restrict__ W,
                     float* __restrict__ out) {
    // y_s[k][z][i] : y[n, k, yy0+i, z] at y_s[k*64 + z*4 + i]  (32 KiB)
    __shared__ float y_s[128 * 64];

    const int tid  = threadIdx.x;
    const int lane = tid & 63;
    const int zz   = lane & 15;       // z-block index (16)
    const int q    = (lane >> 4) & 3; // b2 index (4)
    const int wave = tid >> 6;        // 0..3

    const int bid = blockIdx.x;
    const int pc  = bid & 63;         // p chunk (64 chunks of 16)
    const int yyg = (bid >> 6) & 3;   // yy group (4 groups of 4)
    const int n   = bid >> 8;         // batch (8)

    const int p0  = pc * 16 + wave * 4;  // this thread's 4 p values
    const int yy0 = yyg * 4;             // this thread's 4 yy values

    // ---- stage y into LDS with [i][z] -> [z][i] transpose ----
    // coalesced float4 global loads; 4 scattered ds_write_b32 each (one-time)
    {
        const float* yb = y + n * Y_N_STRIDE + yy0 * 16;
        #pragma unroll
        for (int r = 0; r < 8; ++r) {
            const int f  = tid + r * 256;   // float4 index in [0,2048)
            const int k  = f >> 4;          // 16 float4 per k-row
            const int li = (f & 15) * 4;    // = i*16 + z0 within the k-row
            const int i  = li >> 4;
            const int z0 = li & 15;
            float4 v = *reinterpret_cast<const float4*>(yb + k * 256 + li);
            float* dst = &y_s[k * 64 + z0 * 4 + i];
            dst[0]  = v.x;
            dst[4]  = v.y;
            dst[8]  = v.z;
            dst[12] = v.w;
        }
    }
    __syncthreads();

    // W[k, p0+j, q, 0..3] = Wb[k*16384 + j*16 .. +3]
    const float* Wb = W + p0 * 16 + q * 4;

    float acc[4][4][4]; // [yy][p][r]
    #pragma unroll
    for (int i = 0; i < 4; ++i)
        #pragma unroll
        for (int j = 0; j < 4; ++j)
            #pragma unroll
            for (int r = 0; r < 4; ++r)
                acc[i][j][r] = 0.0f;

    // prefetch W for k=0 into A
    float4 wA[4], wB[4];
    #pragma unroll
    for (int j = 0; j < 4; ++j)
        wA[j] = *reinterpret_cast<const float4*>(Wb + j * 16);

    #pragma unroll 1
    for (int k = 0; k < 128; k += 2) {
        // issue W(k+1) into B; it flies under FMA-A
        #pragma unroll
        for (int j = 0; j < 4; ++j)
            wB[j] = *reinterpret_cast<const float4*>(
                        Wb + (k + 1) * W_K_STRIDE + j * 16);

        // both y reads issued early (immediate-offset ds_read_b128)
        float4 yv0 = *reinterpret_cast<const float4*>(&y_s[k * 64 + zz * 4]);
        float4 yv1 = *reinterpret_cast<const float4*>(&y_s[(k + 1) * 64 + zz * 4]);
        const float* ya0 = &yv0.x;
        const float* ya1 = &yv1.x;

        #pragma unroll
        for (int i = 0; i < 4; ++i) {
            #pragma unroll
            for (int j = 0; j < 4; ++j) {
                acc[i][j][0] = fmaf(ya0[i], wA[j].x, acc[i][j][0]);
                acc[i][j][1] = fmaf(ya0[i], wA[j].y, acc[i][j][1]);
                acc[i][j][2] = fmaf(ya0[i], wA[j].z, acc[i][j][2]);
                acc[i][j][3] = fmaf(ya0[i], wA[j].w, acc[i][j][3]);
            }
        }

        // issue W(k+2) into A (A is dead now); flies under FMA-B
        if (k + 2 < 128) {
            #pragma unroll
            for (int j = 0; j < 4; ++j)
                wA[j] = *reinterpret_cast<const float4*>(
                            Wb + (k + 2) * W_K_STRIDE + j * 16);
        }

        #pragma unroll
        for (int i = 0; i < 4; ++i) {
            #pragma unroll
            for (int j = 0; j < 4; ++j) {
                acc[i][j][0] = fmaf(ya1[i], wB[j].x, acc[i][j][0]);
                acc[i][j][1] = fmaf(ya1[i], wB[j].y, acc[i][j][1]);
                acc[i][j][2] = fmaf(ya1[i], wB[j].z, acc[i][j][2]);
                acc[i][j][3] = fmaf(ya1[i], wB[j].w, acc[i][j][3]);
            }
        }
    }

    // out[n, p0+j, (yy0+i)*4+q, zz*4 + 0..3] — 1 KiB contiguous per wave instr
    float* ob = out + (size_t)n * OUT_N_STRIDE + zz * 4;
    #pragma unroll
    for (int i = 0; i < 4; ++i) {
        const int Y = (yy0 + i) * 4 + q;
        #pragma unroll
        for (int j = 0; j < 4; ++j) {
            float4 v = make_float4(acc[i][j][0], acc[i][j][1],
                                   acc[i][j][2], acc[i][j][3]);
            *reinterpret_cast<float4*>(ob + (p0 + j) * 4096 + Y * 64) = v;
        }
    }
}

extern "C" void kernel_launch(void* const* d_in, const int* in_sizes, int n_in,
                              void* d_out, int out_size, void* d_ws, size_t ws_size,
                              hipStream_t stream) {
    const float* y = (const float*)d_in[0];
    const float* W = (const float*)d_in[1];
    float* out = (float*)d_out;

    // grid: 8 n * 4 yy-groups * 64 p-chunks
    dim3 grid(2048);
    dim3 block(256);
    backproj_kernel<<<grid, block, 0, stream>>>(y, W, out);
}